// Round 19
// baseline (271.214 us; speedup 1.0000x reference)
//
#include <hip/hip_runtime.h>

#define T_TASKS 64
#define B_SEQS 262144
#define BLOCK 256
#define CHUNKS 4              // 4 waves = 4 contiguous t-chunks of 16 rows
#define TPC 16                // t-steps per chunk (per wave)
#define PAIRS 128             // pairs per block (256 seqs)

#define POS_BIG  3.402823466e+38f
#define NEG_BIG -3.402823466e+38f

typedef int v4i __attribute__((ext_vector_type(4)));
typedef int v2i __attribute__((ext_vector_type(2)));

// cap_table[id] = 0.01 * CAP_MATRIX[:,id], float4-padded.
__constant__ float c_capT[13][4] = {
    {0.00f, 0.00f, 0.00f, 0.f}, {0.33f, 0.33f, 0.33f, 0.f},
    {0.50f, 0.49f, 0.42f, 0.f}, {0.43f, 0.39f, 0.39f, 0.f},
    {0.56f, 0.58f, 0.44f, 0.f}, {0.67f, 0.67f, 0.52f, 0.f},
    {0.62f, 0.60f, 0.49f, 0.f}, {0.47f, 0.54f, 0.42f, 0.f},
    {0.50f, 0.52f, 0.45f, 0.f}, {0.51f, 0.52f, 0.46f, 0.f},
    {0.64f, 0.67f, 0.52f, 0.f}, {0.64f, 0.69f, 0.53f, 0.f},
    {0.68f, 0.71f, 0.56f, 0.f},
};

// scan step = clamp-composition (validated absmax=0 in R5/R11/R14/R17/R18):
// med3(x, su?o:-INF, fa?o:+INF) == {max(x,o) | min(x,o) | x}
#define STEP(l, h, A, B)                          \
    l = __builtin_amdgcn_fmed3f(l, A, B);         \
    h = __builtin_amdgcn_fmed3f(h, A, B);

#define GLOAD4(dst, ptr) \
    asm volatile("global_load_dwordx4 %0, %1, off" : "=v"(dst) : "v"(ptr))
#define GLOAD2(dst, ptr) \
    asm volatile("global_load_dwordx2 %0, %1, off" : "=v"(dst) : "v"(ptr))
#define WAITC(N)                                                  \
    asm volatile("s_waitcnt vmcnt(" #N ")" ::: "memory");         \
    __builtin_amdgcn_sched_barrier(0);

__global__ __launch_bounds__(BLOCK, 4) void trust_kernel(
    const v4i* __restrict__ perf2,    // (T, B/2) int4 = perf for seq pair
    const v2i* __restrict__ obs2,     // (T, B/2) int2 = obsids for seq pair
    const int* __restrict__ predids,  // (B)
    const float* __restrict__ betas,  // (3)
    const float* __restrict__ zetas,  // (3)
    float* __restrict__ out)          // (B)
{
    __shared__ float4 s_cap[13];
    __shared__ float  s_lh[CHUNKS][2 * PAIRS][7];   // 4 x 256 x 7 = 28 KiB

    if (threadIdx.x < 13)
        s_cap[threadIdx.x] = *(const float4*)&c_capT[threadIdx.x][0];
    __syncthreads();

    const int tid = threadIdx.x;
    const int wv  = tid >> 6;            // wave = t-chunk, rows [16wv, 16wv+16)
    const int ln  = tid & 63;            // lane 0..63
    const size_t RS = B_SEQS / 2;        // row stride in pairs (131072)
    const size_t pairBase = (size_t)blockIdx.x * PAIRS;

    // Per row, this wave reads 2 KB contiguous perf (2 x 1KB back-to-back)
    // and 1 KB contiguous obs (2 x 512B) -> DRAM-row-friendly.
    const v4i* ap0 = perf2 + (size_t)(wv * TPC) * RS + pairBase + ln;       // pairs [0,64)
    const v4i* ap1 = ap0 + 64;                                              // pairs [64,128)
    const v2i* bp0 = obs2  + (size_t)(wv * TPC) * RS + pairBase + ln;
    const v2i* bp1 = bp0 + 64;

    v4i pfA0, pfB0, pfA1, pfB1;
    v2i idA0, idB0, idA1, idB1;

#define ISSUE(S)                                        \
    GLOAD4(pfA##S, ap0);  GLOAD4(pfB##S, ap1);          \
    ap0 += RS;  ap1 += RS;                              \
    GLOAD2(idA##S, bp0);  GLOAD2(idB##S, bp1);          \
    bp0 += RS;  bp1 += RS;

    // pair A = pairBase+ln (seqs 2ln, 2ln+1); pair B = pairBase+64+ln
    float la0=NEG_BIG, la1=NEG_BIG, la2=NEG_BIG, ha0=POS_BIG, ha1=POS_BIG, ha2=POS_BIG;
    float lb0=NEG_BIG, lb1=NEG_BIG, lb2=NEG_BIG, hb0=POS_BIG, hb1=POS_BIG, hb2=POS_BIG;
    float lc0=NEG_BIG, lc1=NEG_BIG, lc2=NEG_BIG, hc0=POS_BIG, hc1=POS_BIG, hc2=POS_BIG;
    float ld0=NEG_BIG, ld1=NEG_BIG, ld2=NEG_BIG, hd0=POS_BIG, hd1=POS_BIG, hd2=POS_BIG;

#define CONSUME12(pf, idv, l0,l1,l2,h0,h1,h2, m0,m1,m2,g0,g1,g2)             \
    {                                                                        \
        const float4 oa = s_cap[(idv).x];                                    \
        const float4 ob = s_cap[(idv).y];                                    \
        const bool sx = ((pf).x == 0) && ((pf).y != 0);                      \
        const bool fx = ((pf).x != 0) && ((pf).y == 0);                      \
        const bool sy = ((pf).z == 0) && ((pf).w != 0);                      \
        const bool fy = ((pf).z != 0) && ((pf).w == 0);                      \
        const float Ax0 = sx ? oa.x : NEG_BIG, Bx0 = fx ? oa.x : POS_BIG;    \
        const float Ax1 = sx ? oa.y : NEG_BIG, Bx1 = fx ? oa.y : POS_BIG;    \
        const float Ax2 = sx ? oa.z : NEG_BIG, Bx2 = fx ? oa.z : POS_BIG;    \
        const float Ay0 = sy ? ob.x : NEG_BIG, By0 = fy ? ob.x : POS_BIG;    \
        const float Ay1 = sy ? ob.y : NEG_BIG, By1 = fy ? ob.y : POS_BIG;    \
        const float Ay2 = sy ? ob.z : NEG_BIG, By2 = fy ? ob.z : POS_BIG;    \
        STEP(l0, h0, Ax0, Bx0)                                               \
        STEP(l1, h1, Ax1, Bx1)                                               \
        STEP(l2, h2, Ax2, Bx2)                                               \
        STEP(m0, g0, Ay0, By0)                                               \
        STEP(m1, g1, Ay1, By1)                                               \
        STEP(m2, g2, Ay2, By2)                                               \
    }

#define CONSUME_SLOT(S)                                                          \
    CONSUME12(pfA##S, idA##S, la0,la1,la2,ha0,ha1,ha2, lb0,lb1,lb2,hb0,hb1,hb2)  \
    CONSUME12(pfB##S, idB##S, lc0,lc1,lc2,hc0,hc1,hc2, ld0,ld1,ld2,hd0,hd1,hd2)

    // 2-slot ring over 16 rows: 8 loads (2 rows) in flight, counted waits.
    ISSUE(0) ISSUE(1)                                   // rows 0,1
    WAITC(4) CONSUME_SLOT(0) ISSUE(0)                   // row 0, issue row 2
    WAITC(4) CONSUME_SLOT(1) ISSUE(1)                   // row 1, issue row 3
    WAITC(4) CONSUME_SLOT(0) ISSUE(0)                   // row 2, issue row 4
    WAITC(4) CONSUME_SLOT(1) ISSUE(1)                   // row 3, issue row 5
    WAITC(4) CONSUME_SLOT(0) ISSUE(0)                   // row 4, issue row 6
    WAITC(4) CONSUME_SLOT(1) ISSUE(1)                   // row 5, issue row 7
    WAITC(4) CONSUME_SLOT(0) ISSUE(0)                   // row 6, issue row 8
    WAITC(4) CONSUME_SLOT(1) ISSUE(1)                   // row 7, issue row 9
    WAITC(4) CONSUME_SLOT(0) ISSUE(0)                   // row 8, issue row 10
    WAITC(4) CONSUME_SLOT(1) ISSUE(1)                   // row 9, issue row 11
    WAITC(4) CONSUME_SLOT(0) ISSUE(0)                   // row 10, issue row 12
    WAITC(4) CONSUME_SLOT(1) ISSUE(1)                   // row 11, issue row 13
    WAITC(4) CONSUME_SLOT(0) ISSUE(0)                   // row 12, issue row 14
    WAITC(4) CONSUME_SLOT(1) ISSUE(1)                   // row 13, issue row 15
    WAITC(4) CONSUME_SLOT(0)                            // row 14
    WAITC(0) CONSUME_SLOT(1)                            // row 15
#undef CONSUME_SLOT
#undef CONSUME12
#undef ISSUE

    // lane ln: pair A -> local seqs 2ln, 2ln+1; pair B -> 128+2ln, 129+2ln
    {
        float* p;
        p = &s_lh[wv][2 * ln][0];
        p[0]=la0; p[1]=la1; p[2]=la2; p[3]=ha0; p[4]=ha1; p[5]=ha2;
        p = &s_lh[wv][2 * ln + 1][0];
        p[0]=lb0; p[1]=lb1; p[2]=lb2; p[3]=hb0; p[4]=hb1; p[5]=hb2;
        p = &s_lh[wv][128 + 2 * ln][0];
        p[0]=lc0; p[1]=lc1; p[2]=lc2; p[3]=hc0; p[4]=hc1; p[5]=hc2;
        p = &s_lh[wv][129 + 2 * ln][0];
        p[0]=ld0; p[1]=ld1; p[2]=ld2; p[3]=hd0; p[4]=hd1; p[5]=hd2;
    }
    __syncthreads();

    // ---- every thread folds one sequence across 4 chunks, then logistic ----
    {
        float x0 = 0.0f, x1 = 0.0f, x2 = 0.0f;
        #pragma unroll
        for (int cc = 0; cc < CHUNKS; ++cc) {
            const float* q = &s_lh[cc][tid][0];
            x0 = fminf(fmaxf(x0, q[0]), q[3]);
            x1 = fminf(fmaxf(x1, q[1]), q[4]);
            x2 = fminf(fmaxf(x2, q[2]), q[5]);
        }
        const size_t seq = (size_t)blockIdx.x * (2 * PAIRS) + tid;
        const int pid = predids[seq];
        const float4 r = s_cap[pid];

        const float q0 = betas[0] * (r.x - x0);
        const float q1 = betas[1] * (r.y - x1);
        const float q2 = betas[2] * (r.z - x2);

        const float t0 = powf(1.0f + expf(q0), -zetas[0]);
        const float t1 = powf(1.0f + expf(q1), -zetas[1]);
        const float t2 = powf(1.0f + expf(q2), -zetas[2]);

        out[seq] = t0 * t1 * t2;
    }
}

extern "C" void kernel_launch(void* const* d_in, const int* in_sizes, int n_in,
                              void* d_out, int out_size, void* d_ws, size_t ws_size,
                              hipStream_t stream) {
    // d_in[0] = inptasksobs (unused), d_in[4] = num_obs_tasks (unused)
    const v4i*   perf2   = (const v4i*)d_in[1];   // (T, B, 2) int32 as pair-int4
    const v2i*   obs2    = (const v2i*)d_in[2];   // (T, B, 1) int32 as pair-int2
    const int*   predids = (const int*)d_in[3];   // (B, 1) int32
    const float* betas   = (const float*)d_in[5];
    const float* zetas   = (const float*)d_in[6];
    float* out = (float*)d_out;

    const int blocks = B_SEQS / (2 * PAIRS);      // 1024 blocks, 256 seqs each
    trust_kernel<<<blocks, BLOCK, 0, stream>>>(perf2, obs2, predids, betas, zetas, out);
}